// Round 1
// baseline (1051.605 us; speedup 1.0000x reference)
//
#include <hip/hip_runtime.h>

#define D 128
#define NH 8
#define CH 16
#define NEG 0.2f
#define BN_EPS 1e-5f

// ---------------- CSR build ----------------
__global__ void k_hist(const int* __restrict__ ei, int* __restrict__ deg, int E){
  int e = blockIdx.x*blockDim.x + threadIdx.x;
  if (e < E) atomicAdd(&deg[ei[E + e]], 1);
}

__global__ void k_scan1(const int* __restrict__ deg, int* __restrict__ rp, int* __restrict__ bsum, int n){
  __shared__ int s[256];
  int i = blockIdx.x*256 + threadIdx.x;
  int v = (i < n) ? deg[i] : 0;
  s[threadIdx.x] = v;
  __syncthreads();
  for (int off = 1; off < 256; off <<= 1){
    int t = (threadIdx.x >= off) ? s[threadIdx.x - off] : 0;
    __syncthreads();
    s[threadIdx.x] += t;
    __syncthreads();
  }
  if (i < n) rp[i] = s[threadIdx.x] - v;     // exclusive within block
  if (threadIdx.x == 255) bsum[blockIdx.x] = s[255];
}

__global__ void k_scan2(int* bsum, int nb){
  __shared__ int s[512];
  int v = (threadIdx.x < nb) ? bsum[threadIdx.x] : 0;
  s[threadIdx.x] = v;
  __syncthreads();
  for (int off = 1; off < 512; off <<= 1){
    int t = (threadIdx.x >= off) ? s[threadIdx.x - off] : 0;
    __syncthreads();
    s[threadIdx.x] += t;
    __syncthreads();
  }
  if (threadIdx.x < nb) bsum[threadIdx.x] = s[threadIdx.x] - v;  // exclusive
}

__global__ void k_scan3(int* rp, int* cursor, const int* __restrict__ bsum, int n){
  int i = blockIdx.x*256 + threadIdx.x;
  if (i < n){ int v = rp[i] + bsum[blockIdx.x]; rp[i] = v; cursor[i] = v; }
}

__global__ void k_scatter(const int* __restrict__ ei, int* __restrict__ cursor, int* __restrict__ col, int E){
  int e = blockIdx.x*blockDim.x + threadIdx.x;
  if (e < E){
    int d = ei[E + e];
    int pos = atomicAdd(&cursor[d], 1);
    col[pos] = ei[e];
  }
}

// ---------------- input projection: h = relu(x @ Wp + bp) ----------------
__global__ void k_init(const float* __restrict__ x, const float* __restrict__ Wp,
                       const float* __restrict__ bp, float* __restrict__ h, int n){
  int i = blockIdx.x*blockDim.x + threadIdx.x;
  if (i >= n*D) return;
  int nid = i >> 7, d = i & 127;
  const float* xr = x + nid*16;
  float s = bp[d];
#pragma unroll
  for (int k = 0; k < 16; k++) s += xr[k] * Wp[k*D + d];
  h[i] = s > 0.f ? s : 0.f;
}

// ---------------- tiled fp32 GEMM: xh[n,128] = h[n,128] @ W[128,128] ----------------
// block: 256 thr; tile 128 rows x 128 cols; K in chunks of 32.
// tx = t&15 -> cols {4tx..4tx+3, 64+4tx..}; ty = t>>4 -> rows {8ty..8ty+7}
__global__ __launch_bounds__(256) void k_gemm(const float* __restrict__ hin,
                                              const float* __restrict__ W,
                                              float* __restrict__ xh, int n){
  __shared__ float Wl[32*128];      // [k][d]
  __shared__ float hL[128*33];      // [r][k], pad 33 to break bank conflicts
  int t  = threadIdx.x;
  int tx = t & 15, ty = t >> 4;
  int n0 = blockIdx.x * 128;

  float acc[8][8];
#pragma unroll
  for (int i = 0; i < 8; i++)
#pragma unroll
    for (int j = 0; j < 8; j++) acc[i][j] = 0.f;

  for (int kc = 0; kc < 128; kc += 32){
    // stage W chunk: 32x128 = 1024 float4
#pragma unroll
    for (int i = 0; i < 4; i++){
      int fi = t + i*256;           // float4 index
      int k = fi >> 5, d4 = fi & 31;
      float4 w4 = *(const float4*)(W + (kc + k)*D + d4*4);
      Wl[k*128 + d4*4 + 0] = w4.x; Wl[k*128 + d4*4 + 1] = w4.y;
      Wl[k*128 + d4*4 + 2] = w4.z; Wl[k*128 + d4*4 + 3] = w4.w;
    }
    // stage h chunk: 128 rows x 32 k = 1024 float4 (8 float4 per row)
#pragma unroll
    for (int i = 0; i < 4; i++){
      int fi = t + i*256;
      int r = fi >> 3, k4 = fi & 7;
      int row = n0 + r;
      float4 v = make_float4(0.f,0.f,0.f,0.f);
      if (row < n) v = *(const float4*)(hin + (size_t)row*D + kc + k4*4);
      hL[r*33 + k4*4 + 0] = v.x; hL[r*33 + k4*4 + 1] = v.y;
      hL[r*33 + k4*4 + 2] = v.z; hL[r*33 + k4*4 + 3] = v.w;
    }
    __syncthreads();

    for (int k = 0; k < 32; k++){
      float4 w0 = *(const float4*)(Wl + k*128 + tx*4);
      float4 w1 = *(const float4*)(Wl + k*128 + 64 + tx*4);
      float hv[8];
#pragma unroll
      for (int i = 0; i < 8; i++) hv[i] = hL[(ty*8 + i)*33 + k];
#pragma unroll
      for (int i = 0; i < 8; i++){
        acc[i][0] += hv[i]*w0.x; acc[i][1] += hv[i]*w0.y;
        acc[i][2] += hv[i]*w0.z; acc[i][3] += hv[i]*w0.w;
        acc[i][4] += hv[i]*w1.x; acc[i][5] += hv[i]*w1.y;
        acc[i][6] += hv[i]*w1.z; acc[i][7] += hv[i]*w1.w;
      }
    }
    __syncthreads();
  }

#pragma unroll
  for (int i = 0; i < 8; i++){
    int row = n0 + ty*8 + i;
    if (row < n){
      float4 o0 = make_float4(acc[i][0], acc[i][1], acc[i][2], acc[i][3]);
      float4 o1 = make_float4(acc[i][4], acc[i][5], acc[i][6], acc[i][7]);
      *(float4*)(xh + (size_t)row*D + tx*4)      = o0;
      *(float4*)(xh + (size_t)row*D + 64 + tx*4) = o1;
    }
  }
}

// ---------------- per-head attention scores ----------------
__global__ void k_scores(const float* __restrict__ xh, const float* __restrict__ asrc,
                         const float* __restrict__ adst, float* __restrict__ a_src,
                         float* __restrict__ a_dst, int n){
  int i = blockIdx.x*blockDim.x + threadIdx.x;
  if (i >= n*NH) return;
  int nid = i >> 3, hh = i & 7;
  const float4* xp = (const float4*)(xh + (size_t)nid*D + hh*CH);
  const float4* ap = (const float4*)(asrc + hh*CH);
  const float4* bp_ = (const float4*)(adst + hh*CH);
  float s1 = 0.f, s2 = 0.f;
#pragma unroll
  for (int q = 0; q < 4; q++){
    float4 xv = xp[q]; float4 av = ap[q]; float4 bv = bp_[q];
    s1 += xv.x*av.x + xv.y*av.y + xv.z*av.z + xv.w*av.w;
    s2 += xv.x*bv.x + xv.y*bv.y + xv.z*bv.z + xv.w*bv.w;
  }
  a_src[i] = s1; a_dst[i] = s2;
}

// ---------------- per-node online-softmax aggregation ----------------
// one block (128 thr) per dst node; thread t: head t>>4, channel t&15
__global__ __launch_bounds__(128) void k_agg(const float* __restrict__ xh,
                                             const float* __restrict__ a_src,
                                             const float* __restrict__ a_dst,
                                             const int* __restrict__ rp,
                                             const int* __restrict__ deg,
                                             const int* __restrict__ col,
                                             const float* __restrict__ bg,
                                             float* __restrict__ hout, int n){
  int nid = blockIdx.x;
  int t = threadIdx.x;
  int hh = t >> 4;
  float adst = a_dst[nid*NH + hh];
  // self loop first
  float e0 = a_src[nid*NH + hh] + adst;
  e0 = e0 > 0.f ? e0 : NEG*e0;
  float m = e0;
  float denom = 1.0f;
  float acc = xh[(size_t)nid*D + t];
  int start = rp[nid], cnt = deg[nid];
  for (int j = 0; j < cnt; j++){
    int s = col[start + j];
    float e = a_src[s*NH + hh] + adst;
    e = e > 0.f ? e : NEG*e;
    float xv = xh[(size_t)s*D + t];
    if (e > m){
      float r = __expf(m - e);
      denom *= r; acc *= r; m = e;
    }
    float w = __expf(e - m);
    denom += w;
    acc += w * xv;
  }
  hout[(size_t)nid*D + t] = acc/denom + bg[t];
}

// ---------------- BatchNorm ----------------
__global__ __launch_bounds__(256) void k_bnstats(const float* __restrict__ h, float* __restrict__ sums, int n){
  int c = threadIdx.x & 127;
  int half = threadIdx.x >> 7;
  float s = 0.f, s2 = 0.f;
  for (int r = blockIdx.x*2 + half; r < n; r += gridDim.x*2){
    float v = h[(size_t)r*D + c];
    s += v; s2 += v*v;
  }
  __shared__ float sh[256], sh2[256];
  sh[threadIdx.x] = s; sh2[threadIdx.x] = s2;
  __syncthreads();
  if (half == 0){
    s  = sh[c]  + sh[128 + c];
    s2 = sh2[c] + sh2[128 + c];
    atomicAdd(&sums[c], s);
    atomicAdd(&sums[128 + c], s2);
  }
}

__global__ void k_bnapply(float* __restrict__ h, const float* __restrict__ sums,
                          const float* __restrict__ gamma, const float* __restrict__ beta, int n){
  int i = blockIdx.x*blockDim.x + threadIdx.x;
  if (i >= n*D) return;
  int c = i & 127;
  float invn = 1.0f / (float)n;
  float mu = sums[c] * invn;
  float var = sums[128 + c] * invn - mu*mu;
  float inv = rsqrtf(var + BN_EPS);
  float v = (h[i] - mu) * inv * gamma[c] + beta[c];
  h[i] = v > 0.f ? v : 0.f;
}

// ---------------- global mean pool (batch sorted -> binary search) ----------------
__global__ __launch_bounds__(128) void k_pool(const float* __restrict__ h, const int* __restrict__ batch,
                                              float* __restrict__ pooled, int n){
  int g = blockIdx.x;
  __shared__ int se[2];
  if (threadIdx.x == 0){
    int lo = 0, hi = n;
    while (lo < hi){ int mid = (lo + hi) >> 1; if (batch[mid] < g) lo = mid + 1; else hi = mid; }
    se[0] = lo;
    lo = se[0]; hi = n;
    while (lo < hi){ int mid = (lo + hi) >> 1; if (batch[mid] < g + 1) lo = mid + 1; else hi = mid; }
    se[1] = lo;
  }
  __syncthreads();
  int st = se[0], en = se[1];
  float s = 0.f;
  for (int r = st; r < en; r++) s += h[(size_t)r*D + threadIdx.x];
  float cnt = (float)(en - st);
  pooled[(size_t)g*D + threadIdx.x] = s / fmaxf(cnt, 1.0f);
}

// ---------------- output heads ----------------
__global__ __launch_bounds__(64) void k_heads(const float* __restrict__ pooled,
                                              const float* __restrict__ hW1, const float* __restrict__ hb1,
                                              const float* __restrict__ hW2, const float* __restrict__ hb2,
                                              float* __restrict__ out){
  int g = blockIdx.x;
  int m = threadIdx.x;
  __shared__ float sp[128];
  sp[m]      = pooled[(size_t)g*D + m];
  sp[m + 64] = pooled[(size_t)g*D + m + 64];
  __syncthreads();
#pragma unroll
  for (int k = 0; k < 3; k++){
    float acc = hb1[k*64 + m];
    const float* w = hW1 + k*8192 + m;
    for (int d = 0; d < 128; d++) acc += sp[d] * w[d*64];
    float val = fmaxf(acc, 0.f) * hW2[k*64 + m];
    for (int off = 32; off; off >>= 1) val += __shfl_down(val, off);
    if (m == 0) out[g*3 + k] = val + hb2[k];
  }
}

// ---------------- launch ----------------
extern "C" void kernel_launch(void* const* d_in, const int* in_sizes, int n_in,
                              void* d_out, int out_size, void* d_ws, size_t ws_size,
                              hipStream_t stream){
  const float* x    = (const float*)d_in[0];
  const int*   ei   = (const int*)d_in[1];
  const int*   batch= (const int*)d_in[2];
  const float* Wp   = (const float*)d_in[3];
  const float* bp   = (const float*)d_in[4];
  const float* Wg   = (const float*)d_in[5];
  const float* asrc = (const float*)d_in[6];
  const float* adst = (const float*)d_in[7];
  const float* bg   = (const float*)d_in[8];
  const float* gamma= (const float*)d_in[9];
  const float* beta = (const float*)d_in[10];
  const float* hW1  = (const float*)d_in[11];
  const float* hb1  = (const float*)d_in[12];
  const float* hW2  = (const float*)d_in[13];
  const float* hb2  = (const float*)d_in[14];
  float* out = (float*)d_out;

  const int E = in_sizes[1] / 2;
  const int N = in_sizes[2];
  const int G = out_size / 3;

  char* w = (char*)d_ws;
  auto alloc = [&](size_t bytes){ char* p = w; w += (bytes + 255) & ~(size_t)255; return p; };
  float* h      = (float*)alloc((size_t)N*D*4);
  float* xh     = (float*)alloc((size_t)N*D*4);
  float* a_src  = (float*)alloc((size_t)N*NH*4);
  float* a_dst  = (float*)alloc((size_t)N*NH*4);
  int*   deg    = (int*)  alloc((size_t)N*4);
  int*   rp     = (int*)  alloc((size_t)N*4);
  int*   cursor = (int*)  alloc((size_t)N*4);
  int*   col    = (int*)  alloc((size_t)E*4);
  int*   bsum   = (int*)  alloc(512*4);
  float* bnsum  = (float*)alloc(256*4);
  float* pooled = (float*)alloc((size_t)G*D*4);

  const int nb = (N + 255) / 256;

  hipMemsetAsync(deg, 0, (size_t)N*4, stream);
  k_hist   <<<(E + 255)/256, 256, 0, stream>>>(ei, deg, E);
  k_scan1  <<<nb, 256, 0, stream>>>(deg, rp, bsum, N);
  k_scan2  <<<1, 512, 0, stream>>>(bsum, nb);
  k_scan3  <<<nb, 256, 0, stream>>>(rp, cursor, bsum, N);
  k_scatter<<<(E + 255)/256, 256, 0, stream>>>(ei, cursor, col, E);

  k_init<<<(N*D + 255)/256, 256, 0, stream>>>(x, Wp, bp, h, N);

  for (int l = 0; l < 4; l++){
    k_gemm  <<<(N + 127)/128, 256, 0, stream>>>(h, Wg + l*D*D, xh, N);
    k_scores<<<(N*NH + 255)/256, 256, 0, stream>>>(xh, asrc + l*NH*CH, adst + l*NH*CH, a_src, a_dst, N);
    k_agg   <<<N, 128, 0, stream>>>(xh, a_src, a_dst, rp, deg, col, bg + l*D, h, N);
    hipMemsetAsync(bnsum, 0, 256*4, stream);
    k_bnstats<<<256, 256, 0, stream>>>(h, bnsum, N);
    k_bnapply<<<(N*D + 255)/256, 256, 0, stream>>>(h, bnsum, gamma + l*D, beta + l*D, N);
  }

  k_pool <<<G, 128, 0, stream>>>(h, batch, pooled, N);
  k_heads<<<G, 64, 0, stream>>>(pooled, hW1, hb1, hW2, hb2, out);
}

// Round 2
// 938.165 us; speedup vs baseline: 1.1209x; 1.1209x over previous
//
#include <hip/hip_runtime.h>

#define D 128
#define NH 8
#define CH 16
#define NEG 0.2f
#define BN_EPS 1e-5f

typedef unsigned int uint;
typedef unsigned short ushort;

__device__ __forceinline__ float bf_lo(uint u){ return __uint_as_float(u << 16); }
__device__ __forceinline__ float bf_hi(uint u){ return __uint_as_float(u & 0xffff0000u); }
__device__ __forceinline__ float bf2f(ushort s){ return __uint_as_float(((uint)s) << 16); }
__device__ __forceinline__ ushort f2b(float f){
  uint u = __float_as_uint(f);
  u += 0x7fffu + ((u >> 16) & 1u);      // round-to-nearest-even
  return (ushort)(u >> 16);
}

// ---------------- CSR build ----------------
__global__ void k_hist(const int* __restrict__ ei, int* __restrict__ deg, int E){
  int e = blockIdx.x*blockDim.x + threadIdx.x;
  if (e < E) atomicAdd(&deg[ei[E + e]], 1);
}

__global__ void k_scan1(const int* __restrict__ deg, int* __restrict__ rp, int* __restrict__ bsum, int n){
  __shared__ int s[256];
  int i = blockIdx.x*256 + threadIdx.x;
  int v = (i < n) ? deg[i] : 0;
  s[threadIdx.x] = v;
  __syncthreads();
  for (int off = 1; off < 256; off <<= 1){
    int t = (threadIdx.x >= off) ? s[threadIdx.x - off] : 0;
    __syncthreads();
    s[threadIdx.x] += t;
    __syncthreads();
  }
  if (i < n) rp[i] = s[threadIdx.x] - v;
  if (threadIdx.x == 255) bsum[blockIdx.x] = s[255];
}

__global__ void k_scan2(int* bsum, int nb){
  __shared__ int s[512];
  int v = (threadIdx.x < nb) ? bsum[threadIdx.x] : 0;
  s[threadIdx.x] = v;
  __syncthreads();
  for (int off = 1; off < 512; off <<= 1){
    int t = (threadIdx.x >= off) ? s[threadIdx.x - off] : 0;
    __syncthreads();
    s[threadIdx.x] += t;
    __syncthreads();
  }
  if (threadIdx.x < nb) bsum[threadIdx.x] = s[threadIdx.x] - v;
}

__global__ void k_scan3(int* rp, int* cursor, const int* __restrict__ bsum, int n){
  int i = blockIdx.x*256 + threadIdx.x;
  if (i < n){ int v = rp[i] + bsum[blockIdx.x]; rp[i] = v; cursor[i] = v; }
}

__global__ void k_scatter(const int* __restrict__ ei, int* __restrict__ cursor, int* __restrict__ col, int E){
  int e = blockIdx.x*blockDim.x + threadIdx.x;
  if (e < E){
    int d = ei[E + e];
    int pos = atomicAdd(&cursor[d], 1);
    col[pos] = ei[e];
  }
}

// ---------------- input projection: h = relu(x @ Wp + bp), bf16 out ----------------
__global__ void k_init(const float* __restrict__ x, const float* __restrict__ Wp,
                       const float* __restrict__ bp, ushort* __restrict__ h, int n){
  int i = blockIdx.x*blockDim.x + threadIdx.x;
  if (i >= n*D) return;
  int nid = i >> 7, d = i & 127;
  const float* xr = x + nid*16;
  float s = bp[d];
#pragma unroll
  for (int k = 0; k < 16; k++) s += xr[k] * Wp[k*D + d];
  h[i] = f2b(s > 0.f ? s : 0.f);
}

// ---------------- GEMM with fused BN(scale/shift)+ReLU on A-load ----------------
// xh[n,128](bf16) = relu(scale*h + shift) @ W[128,128](fp32)
__global__ __launch_bounds__(256) void k_gemm(const ushort* __restrict__ hin,
                                              const float* __restrict__ W,
                                              ushort* __restrict__ xh,
                                              const float* __restrict__ bnsc, int n){
  __shared__ float Wl[32*128];      // [k][d]
  __shared__ float hL[128*33];      // [r][k], pad to 33
  __shared__ float sS[128], sB[128];
  int t  = threadIdx.x;
  int tx = t & 15, ty = t >> 4;
  int n0 = blockIdx.x * 128;

  if (t < 128) sS[t] = bnsc[t];
  else         sB[t - 128] = bnsc[t];

  float acc[8][8];
#pragma unroll
  for (int i = 0; i < 8; i++)
#pragma unroll
    for (int j = 0; j < 8; j++) acc[i][j] = 0.f;

  __syncthreads();   // sS/sB visible

  for (int kc = 0; kc < 128; kc += 32){
    // stage W chunk: 32x128 fp32 = 1024 float4
#pragma unroll
    for (int i = 0; i < 4; i++){
      int fi = t + i*256;
      int k = fi >> 5, d4 = fi & 31;
      float4 w4 = *(const float4*)(W + (kc + k)*D + d4*4);
      Wl[k*128 + d4*4 + 0] = w4.x; Wl[k*128 + d4*4 + 1] = w4.y;
      Wl[k*128 + d4*4 + 2] = w4.z; Wl[k*128 + d4*4 + 3] = w4.w;
    }
    // stage h chunk: 128 rows x 32 k bf16 = 512 x 16B, BN+relu applied
#pragma unroll
    for (int i = 0; i < 2; i++){
      int u = t + i*256;
      int r = u >> 2, k8 = u & 3;
      int row = n0 + r;
      uint4 v = make_uint4(0,0,0,0);
      if (row < n) v = *(const uint4*)(hin + (size_t)row*D + kc + k8*8);
      float f[8] = { bf_lo(v.x), bf_hi(v.x), bf_lo(v.y), bf_hi(v.y),
                     bf_lo(v.z), bf_hi(v.z), bf_lo(v.w), bf_hi(v.w) };
      int kb = k8*8;
#pragma unroll
      for (int j = 0; j < 8; j++){
        int kk = kc + kb + j;
        float xv = f[j]*sS[kk] + sB[kk];
        hL[r*33 + kb + j] = xv > 0.f ? xv : 0.f;
      }
    }
    __syncthreads();

    for (int k = 0; k < 32; k++){
      float4 w0 = *(const float4*)(Wl + k*128 + tx*4);
      float4 w1 = *(const float4*)(Wl + k*128 + 64 + tx*4);
      float hv[8];
#pragma unroll
      for (int i = 0; i < 8; i++) hv[i] = hL[(ty*8 + i)*33 + k];
#pragma unroll
      for (int i = 0; i < 8; i++){
        acc[i][0] += hv[i]*w0.x; acc[i][1] += hv[i]*w0.y;
        acc[i][2] += hv[i]*w0.z; acc[i][3] += hv[i]*w0.w;
        acc[i][4] += hv[i]*w1.x; acc[i][5] += hv[i]*w1.y;
        acc[i][6] += hv[i]*w1.z; acc[i][7] += hv[i]*w1.w;
      }
    }
    __syncthreads();
  }

#pragma unroll
  for (int i = 0; i < 8; i++){
    int row = n0 + ty*8 + i;
    if (row < n){
      ushort4 o0, o1;
      o0.x = f2b(acc[i][0]); o0.y = f2b(acc[i][1]); o0.z = f2b(acc[i][2]); o0.w = f2b(acc[i][3]);
      o1.x = f2b(acc[i][4]); o1.y = f2b(acc[i][5]); o1.z = f2b(acc[i][6]); o1.w = f2b(acc[i][7]);
      *(ushort4*)(xh + (size_t)row*D + tx*4)      = o0;
      *(ushort4*)(xh + (size_t)row*D + 64 + tx*4) = o1;
    }
  }
}

// ---------------- per-head attention scores (bf16 xh) ----------------
__global__ void k_scores(const ushort* __restrict__ xh, const float* __restrict__ asrc,
                         const float* __restrict__ adst, float* __restrict__ a_src,
                         float* __restrict__ a_dst, int n){
  int i = blockIdx.x*blockDim.x + threadIdx.x;
  if (i >= n*NH) return;
  int nid = i >> 3, hh = i & 7;
  const uint4* xp = (const uint4*)(xh + (size_t)nid*D + hh*CH);
  const float* ap = asrc + hh*CH;
  const float* bp_ = adst + hh*CH;
  float s1 = 0.f, s2 = 0.f;
#pragma unroll
  for (int q = 0; q < 2; q++){
    uint4 v = xp[q];
    float f[8] = { bf_lo(v.x), bf_hi(v.x), bf_lo(v.y), bf_hi(v.y),
                   bf_lo(v.z), bf_hi(v.z), bf_lo(v.w), bf_hi(v.w) };
#pragma unroll
    for (int j = 0; j < 8; j++){
      s1 += f[j] * ap[q*8 + j];
      s2 += f[j] * bp_[q*8 + j];
    }
  }
  a_src[i] = s1; a_dst[i] = s2;
}

// ---------------- per-node online-softmax aggregation (bf16 in/out) ----------------
__global__ __launch_bounds__(128) void k_agg(const ushort* __restrict__ xh,
                                             const float* __restrict__ a_src,
                                             const float* __restrict__ a_dst,
                                             const int* __restrict__ rp,
                                             const int* __restrict__ deg,
                                             const int* __restrict__ col,
                                             const float* __restrict__ bg,
                                             ushort* __restrict__ hout, int n){
  int nid = blockIdx.x;
  int t = threadIdx.x;
  int hh = t >> 4;
  float adst = a_dst[nid*NH + hh];
  float e0 = a_src[nid*NH + hh] + adst;
  e0 = e0 > 0.f ? e0 : NEG*e0;
  float m = e0;
  float denom = 1.0f;
  float acc = bf2f(xh[(size_t)nid*D + t]);
  int start = rp[nid], cnt = deg[nid];
  for (int j = 0; j < cnt; j++){
    int s = col[start + j];
    float e = a_src[s*NH + hh] + adst;
    e = e > 0.f ? e : NEG*e;
    float xv = bf2f(xh[(size_t)s*D + t]);
    if (e > m){
      float r = __expf(m - e);
      denom *= r; acc *= r; m = e;
    }
    float w = __expf(e - m);
    denom += w;
    acc += w * xv;
  }
  hout[(size_t)nid*D + t] = f2b(acc/denom + bg[t]);
}

// ---------------- BatchNorm stats over bf16 h ----------------
__global__ __launch_bounds__(256) void k_bnstats(const ushort* __restrict__ h, float* __restrict__ sums, int n){
  int c = threadIdx.x & 127;
  int half = threadIdx.x >> 7;
  float s = 0.f, s2 = 0.f;
  for (int r = blockIdx.x*2 + half; r < n; r += gridDim.x*2){
    float v = bf2f(h[(size_t)r*D + c]);
    s += v; s2 += v*v;
  }
  __shared__ float sh[256], sh2[256];
  sh[threadIdx.x] = s; sh2[threadIdx.x] = s2;
  __syncthreads();
  if (half == 0){
    s  = sh[c]  + sh[128 + c];
    s2 = sh2[c] + sh2[128 + c];
    atomicAdd(&sums[c], s);
    atomicAdd(&sums[128 + c], s2);
  }
}

// scale/shift for the NEXT consumer: scale = gamma*rsqrt(var+eps), shift = beta - mu*scale
__global__ void k_bnfinal(const float* __restrict__ sums, const float* __restrict__ gamma,
                          const float* __restrict__ beta, float* __restrict__ bnsc, int n){
  int c = threadIdx.x;
  float invn = 1.0f / (float)n;
  float mu = sums[c] * invn;
  float var = sums[128 + c] * invn - mu*mu;
  float sc = gamma[c] * rsqrtf(var + BN_EPS);
  bnsc[c] = sc;
  bnsc[128 + c] = beta[c] - mu*sc;
}

__global__ void k_bnsc_init(float* __restrict__ bnsc){
  int c = threadIdx.x;
  bnsc[c] = 1.0f;
  bnsc[128 + c] = 0.0f;
}

// ---------------- global mean pool with fused BN+ReLU ----------------
__global__ __launch_bounds__(128) void k_pool(const ushort* __restrict__ h, const int* __restrict__ batch,
                                              const float* __restrict__ bnsc,
                                              float* __restrict__ pooled, int n){
  int g = blockIdx.x;
  __shared__ int se[2];
  if (threadIdx.x == 0){
    int lo = 0, hi = n;
    while (lo < hi){ int mid = (lo + hi) >> 1; if (batch[mid] < g) lo = mid + 1; else hi = mid; }
    se[0] = lo;
    lo = se[0]; hi = n;
    while (lo < hi){ int mid = (lo + hi) >> 1; if (batch[mid] < g + 1) lo = mid + 1; else hi = mid; }
    se[1] = lo;
  }
  __syncthreads();
  int st = se[0], en = se[1];
  float sc = bnsc[threadIdx.x], sh = bnsc[128 + threadIdx.x];
  float s = 0.f;
  for (int r = st; r < en; r++){
    float v = bf2f(h[(size_t)r*D + threadIdx.x]) * sc + sh;
    s += v > 0.f ? v : 0.f;
  }
  float cnt = (float)(en - st);
  pooled[(size_t)g*D + threadIdx.x] = s / fmaxf(cnt, 1.0f);
}

// ---------------- output heads ----------------
__global__ __launch_bounds__(64) void k_heads(const float* __restrict__ pooled,
                                              const float* __restrict__ hW1, const float* __restrict__ hb1,
                                              const float* __restrict__ hW2, const float* __restrict__ hb2,
                                              float* __restrict__ out){
  int g = blockIdx.x;
  int m = threadIdx.x;
  __shared__ float sp[128];
  sp[m]      = pooled[(size_t)g*D + m];
  sp[m + 64] = pooled[(size_t)g*D + m + 64];
  __syncthreads();
#pragma unroll
  for (int k = 0; k < 3; k++){
    float acc = hb1[k*64 + m];
    const float* w = hW1 + k*8192 + m;
    for (int d = 0; d < 128; d++) acc += sp[d] * w[d*64];
    float val = fmaxf(acc, 0.f) * hW2[k*64 + m];
    for (int off = 32; off; off >>= 1) val += __shfl_down(val, off);
    if (m == 0) out[g*3 + k] = val + hb2[k];
  }
}

// ---------------- launch ----------------
extern "C" void kernel_launch(void* const* d_in, const int* in_sizes, int n_in,
                              void* d_out, int out_size, void* d_ws, size_t ws_size,
                              hipStream_t stream){
  const float* x    = (const float*)d_in[0];
  const int*   ei   = (const int*)d_in[1];
  const int*   batch= (const int*)d_in[2];
  const float* Wp   = (const float*)d_in[3];
  const float* bp   = (const float*)d_in[4];
  const float* Wg   = (const float*)d_in[5];
  const float* asrc = (const float*)d_in[6];
  const float* adst = (const float*)d_in[7];
  const float* bg   = (const float*)d_in[8];
  const float* gamma= (const float*)d_in[9];
  const float* beta = (const float*)d_in[10];
  const float* hW1  = (const float*)d_in[11];
  const float* hb1  = (const float*)d_in[12];
  const float* hW2  = (const float*)d_in[13];
  const float* hb2  = (const float*)d_in[14];
  float* out = (float*)d_out;

  const int E = in_sizes[1] / 2;
  const int N = in_sizes[2];
  const int G = out_size / 3;

  char* w = (char*)d_ws;
  auto alloc = [&](size_t bytes){ char* p = w; w += (bytes + 255) & ~(size_t)255; return p; };
  ushort* h     = (ushort*)alloc((size_t)N*D*2);
  ushort* xh    = (ushort*)alloc((size_t)N*D*2);
  float* a_src  = (float*)alloc((size_t)N*NH*4);
  float* a_dst  = (float*)alloc((size_t)N*NH*4);
  int*   deg    = (int*)  alloc((size_t)N*4);
  int*   rp     = (int*)  alloc((size_t)N*4);
  int*   cursor = (int*)  alloc((size_t)N*4);
  int*   col    = (int*)  alloc((size_t)E*4);
  int*   bsum   = (int*)  alloc(512*4);
  float* bnsum  = (float*)alloc(256*4);
  float* bnsc   = (float*)alloc(256*4);
  float* pooled = (float*)alloc((size_t)G*D*4);

  const int nb = (N + 255) / 256;

  hipMemsetAsync(deg, 0, (size_t)N*4, stream);
  k_hist   <<<(E + 255)/256, 256, 0, stream>>>(ei, deg, E);
  k_scan1  <<<nb, 256, 0, stream>>>(deg, rp, bsum, N);
  k_scan2  <<<1, 512, 0, stream>>>(bsum, nb);
  k_scan3  <<<nb, 256, 0, stream>>>(rp, cursor, bsum, N);
  k_scatter<<<(E + 255)/256, 256, 0, stream>>>(ei, cursor, col, E);

  k_init<<<(N*D + 255)/256, 256, 0, stream>>>(x, Wp, bp, h, N);
  k_bnsc_init<<<1, 128, 0, stream>>>(bnsc);

  for (int l = 0; l < 4; l++){
    k_gemm  <<<(N + 127)/128, 256, 0, stream>>>(h, Wg + l*D*D, xh, bnsc, N);
    k_scores<<<(N*NH + 255)/256, 256, 0, stream>>>(xh, asrc + l*NH*CH, adst + l*NH*CH, a_src, a_dst, N);
    k_agg   <<<N, 128, 0, stream>>>(xh, a_src, a_dst, rp, deg, col, bg + l*D, h, N);
    hipMemsetAsync(bnsum, 0, 256*4, stream);
    k_bnstats<<<256, 256, 0, stream>>>(h, bnsum, N);
    k_bnfinal<<<1, 128, 0, stream>>>(bnsum, gamma + l*D, beta + l*D, bnsc, N);
  }

  k_pool <<<G, 128, 0, stream>>>(h, batch, bnsc, pooled, N);
  k_heads<<<G, 64, 0, stream>>>(pooled, hW1, hb1, hW2, hb2, out);
}

// Round 3
// 841.458 us; speedup vs baseline: 1.2497x; 1.1149x over previous
//
#include <hip/hip_runtime.h>

#define D 128
#define NH 8
#define CH 16
#define NEG 0.2f
#define BN_EPS 1e-5f

typedef unsigned int uint;
typedef unsigned short ushort;
typedef __attribute__((ext_vector_type(8))) short bfrag;
typedef __attribute__((ext_vector_type(4))) float ffrag;

__device__ __forceinline__ float bf_lo(uint u){ return __uint_as_float(u << 16); }
__device__ __forceinline__ float bf_hi(uint u){ return __uint_as_float(u & 0xffff0000u); }
__device__ __forceinline__ float bf2f(ushort s){ return __uint_as_float(((uint)s) << 16); }
__device__ __forceinline__ ushort f2b(float f){
  uint u = __float_as_uint(f);
  u += 0x7fffu + ((u >> 16) & 1u);      // round-to-nearest-even
  return (ushort)(u >> 16);
}

// ---------------- CSR build ----------------
__global__ void k_hist(const int* __restrict__ ei, int* __restrict__ deg, int E){
  int e = blockIdx.x*blockDim.x + threadIdx.x;
  if (e < E) atomicAdd(&deg[ei[E + e]], 1);
}

__global__ void k_scan1(const int* __restrict__ deg, int* __restrict__ rp, int* __restrict__ bsum, int n){
  __shared__ int s[256];
  int i = blockIdx.x*256 + threadIdx.x;
  int v = (i < n) ? deg[i] : 0;
  s[threadIdx.x] = v;
  __syncthreads();
  for (int off = 1; off < 256; off <<= 1){
    int t = (threadIdx.x >= off) ? s[threadIdx.x - off] : 0;
    __syncthreads();
    s[threadIdx.x] += t;
    __syncthreads();
  }
  if (i < n) rp[i] = s[threadIdx.x] - v;
  if (threadIdx.x == 255) bsum[blockIdx.x] = s[255];
}

__global__ void k_scan2(int* bsum, int nb){
  __shared__ int s[512];
  int v = (threadIdx.x < nb) ? bsum[threadIdx.x] : 0;
  s[threadIdx.x] = v;
  __syncthreads();
  for (int off = 1; off < 512; off <<= 1){
    int t = (threadIdx.x >= off) ? s[threadIdx.x - off] : 0;
    __syncthreads();
    s[threadIdx.x] += t;
    __syncthreads();
  }
  if (threadIdx.x < nb) bsum[threadIdx.x] = s[threadIdx.x] - v;
}

__global__ void k_scan3(int* rp, int* cursor, const int* __restrict__ bsum, int n){
  int i = blockIdx.x*256 + threadIdx.x;
  if (i < n){ int v = rp[i] + bsum[blockIdx.x]; rp[i] = v; cursor[i] = v; }
}

__global__ void k_scatter(const int* __restrict__ ei, int* __restrict__ cursor, int* __restrict__ col, int E){
  int e = blockIdx.x*blockDim.x + threadIdx.x;
  if (e < E){
    int d = ei[E + e];
    int pos = atomicAdd(&cursor[d], 1);
    col[pos] = ei[e];
  }
}

// ---------------- weight prep: WtB[l][n][k] = bf16(Wg[l][k][n]) ----------------
__global__ void k_wprep(const float* __restrict__ Wg, ushort* __restrict__ WtB, int total){
  int i = blockIdx.x*256 + threadIdx.x;
  if (i >= total) return;
  int l = i >> 14, r = i & 16383, nn = r >> 7, kk = r & 127;
  WtB[i] = f2b(Wg[l*16384 + kk*128 + nn]);
}

// ---------------- input projection: h = relu(x @ Wp + bp), bf16 out ----------------
__global__ void k_init(const float* __restrict__ x, const float* __restrict__ Wp,
                       const float* __restrict__ bp, ushort* __restrict__ h, int n){
  int i = blockIdx.x*blockDim.x + threadIdx.x;
  if (i >= n*D) return;
  int nid = i >> 7, d = i & 127;
  const float* xr = x + nid*16;
  float s = bp[d];
#pragma unroll
  for (int k = 0; k < 16; k++) s += xr[k] * Wp[k*D + d];
  h[i] = f2b(s > 0.f ? s : 0.f);
}

// ---------------- MFMA bf16 GEMM, fused BN+ReLU on A-load ----------------
// xh[n,128] = relu(sc*h + sh) @ W ;  A/B bf16, acc fp32.
// block 256 thr = 4 waves; tile 128x128, K chunked by 64.
// wave w owns rows [32w,32w+32): 2 m-tiles x 8 n-tiles of 16x16, K-steps of 32.
__global__ __launch_bounds__(256) void k_gemm(const ushort* __restrict__ hin,
                                              const ushort* __restrict__ WtB,
                                              ushort* __restrict__ xh,
                                              const float* __restrict__ bnsc, int n){
  __shared__ ushort sm[2*128*72];          // hL | wL ; 72 = 64 + 8 pad (16B, keeps alignment)
  __shared__ float sS[128], sB[128];
  ushort* hL = sm;
  ushort* wL = sm + 128*72;
  int t = threadIdx.x;
  int wid = t >> 6, lane = t & 63, l15 = lane & 15, quad = lane >> 4;
  int n0 = blockIdx.x * 128;

  if (t < 128) sS[t] = bnsc[t];
  else         sB[t - 128] = bnsc[t];

  ffrag acc[2][8];
#pragma unroll
  for (int mt = 0; mt < 2; mt++)
#pragma unroll
    for (int nt = 0; nt < 8; nt++) acc[mt][nt] = (ffrag){0.f,0.f,0.f,0.f};

  __syncthreads();

  for (int kc = 0; kc < 128; kc += 64){
    // stage A (h) with BN+ReLU: 128 rows x 64 k = 1024 uint4
#pragma unroll
    for (int i = 0; i < 4; i++){
      int u = t + i*256;
      int r = u >> 3, k8 = u & 7;
      int row = n0 + r;
      uint4 v = make_uint4(0,0,0,0);
      if (row < n) v = *(const uint4*)(hin + (size_t)row*D + kc + k8*8);
      int kb = kc + k8*8;
      float f[8] = { bf_lo(v.x), bf_hi(v.x), bf_lo(v.y), bf_hi(v.y),
                     bf_lo(v.z), bf_hi(v.z), bf_lo(v.w), bf_hi(v.w) };
      union { ushort us[8]; uint4 u4; } o;
#pragma unroll
      for (int j = 0; j < 8; j++){
        float xv = f[j]*sS[kb + j] + sB[kb + j];
        o.us[j] = f2b(xv > 0.f ? xv : 0.f);
      }
      *(uint4*)(hL + r*72 + k8*8) = o.u4;
    }
    // stage B (Wt): 128 n x 64 k = 1024 uint4 (already bf16, [n][k])
#pragma unroll
    for (int i = 0; i < 4; i++){
      int u = t + i*256;
      int r = u >> 3, k8 = u & 7;
      uint4 v = *(const uint4*)(WtB + (size_t)r*D + kc + k8*8);
      *(uint4*)(wL + r*72 + k8*8) = v;
    }
    __syncthreads();

    bfrag a[2][2];
#pragma unroll
    for (int mt = 0; mt < 2; mt++)
#pragma unroll
      for (int ks = 0; ks < 2; ks++)
        a[mt][ks] = *(const bfrag*)(hL + (wid*32 + mt*16 + l15)*72 + ks*32 + quad*8);

#pragma unroll
    for (int nt = 0; nt < 8; nt++){
#pragma unroll
      for (int ks = 0; ks < 2; ks++){
        bfrag b = *(const bfrag*)(wL + (nt*16 + l15)*72 + ks*32 + quad*8);
        acc[0][nt] = __builtin_amdgcn_mfma_f32_16x16x32_bf16(a[0][ks], b, acc[0][nt], 0, 0, 0);
        acc[1][nt] = __builtin_amdgcn_mfma_f32_16x16x32_bf16(a[1][ks], b, acc[1][nt], 0, 0, 0);
      }
    }
    __syncthreads();
  }

  // epilogue: repack C through LDS (row = wid*32+mt*16+quad*4+r, col = nt*16+l15)
  ushort* oL = sm;                          // 128*136 ushorts = 34816 B, fits
#pragma unroll
  for (int mt = 0; mt < 2; mt++)
#pragma unroll
    for (int nt = 0; nt < 8; nt++)
#pragma unroll
      for (int r = 0; r < 4; r++){
        int row = wid*32 + mt*16 + quad*4 + r;
        oL[row*136 + nt*16 + l15] = f2b(acc[mt][nt][r]);
      }
  __syncthreads();
#pragma unroll
  for (int i = 0; i < 8; i++){
    int u = t + i*256;
    int row = u >> 4, c8 = u & 15;
    int grow = n0 + row;
    if (grow < n)
      *(uint4*)(xh + (size_t)grow*D + c8*8) = *(const uint4*)(oL + row*136 + c8*8);
  }
}

// ---------------- per-head attention scores (bf16 xh) ----------------
__global__ void k_scores(const ushort* __restrict__ xh, const float* __restrict__ asrc,
                         const float* __restrict__ adst, float* __restrict__ a_src,
                         float* __restrict__ a_dst, int n){
  int i = blockIdx.x*blockDim.x + threadIdx.x;
  if (i >= n*NH) return;
  int nid = i >> 3, hh = i & 7;
  const uint4* xp = (const uint4*)(xh + (size_t)nid*D + hh*CH);
  const float* ap = asrc + hh*CH;
  const float* bp_ = adst + hh*CH;
  float s1 = 0.f, s2 = 0.f;
#pragma unroll
  for (int q = 0; q < 2; q++){
    uint4 v = xp[q];
    float f[8] = { bf_lo(v.x), bf_hi(v.x), bf_lo(v.y), bf_hi(v.y),
                   bf_lo(v.z), bf_hi(v.z), bf_lo(v.w), bf_hi(v.w) };
#pragma unroll
    for (int j = 0; j < 8; j++){
      s1 += f[j] * ap[q*8 + j];
      s2 += f[j] * bp_[q*8 + j];
    }
  }
  a_src[i] = s1; a_dst[i] = s2;
}

// ---------------- per-node aggregation, chunked parallel gathers ----------------
// one block (128 thr) per dst node; thread t: head t>>4, channel t&15.
// Per chunk of 8 neighbors: parallel-issue all xh gathers (ILP), 64 threads gather
// raw scores, 8 threads (one per head) do softmax weights once, all threads FMA.
__global__ __launch_bounds__(128) void k_agg(const ushort* __restrict__ xh,
                                             const float* __restrict__ a_src,
                                             const float* __restrict__ a_dst,
                                             const int* __restrict__ rp,
                                             const int* __restrict__ deg,
                                             const int* __restrict__ col,
                                             const float* __restrict__ bg,
                                             ushort* __restrict__ hout, int n){
  int nid = blockIdx.x;
  int t = threadIdx.x, hh = t >> 4;
  __shared__ int sIdx[8];
  __shared__ float sSc[8][8];    // raw a_src [j][head]
  __shared__ float sW[8][8];     // softmax weights this chunk [j][head]
  __shared__ float sR[8];        // acc rescale per head
  __shared__ float sM[8], sD[8], sAd[8];

  if (t < 8){
    int h = t;
    float ad = a_dst[nid*NH + h];
    float e0 = a_src[nid*NH + h] + ad;
    e0 = e0 > 0.f ? e0 : NEG*e0;
    sAd[h] = ad; sM[h] = e0; sD[h] = 1.f;
  }
  float acc = bf2f(xh[(size_t)nid*D + t]);   // self loop, weight 1 rel. to m=e0
  int start = rp[nid], cnt = deg[nid];

  for (int c0 = 0; c0 < cnt; c0 += 8){
    int cc = cnt - c0; if (cc > 8) cc = 8;
    __syncthreads();
    if (t < cc) sIdx[t] = col[start + c0 + t];
    __syncthreads();
    // parallel-issue neighbor row gathers (independent loads -> ILP)
    int idx[8];
#pragma unroll
    for (int j = 0; j < 8; j++) idx[j] = (j < cc) ? sIdx[j] : nid;
    float xv[8];
#pragma unroll
    for (int j = 0; j < 8; j++) xv[j] = bf2f(xh[(size_t)idx[j]*D + t]);
    // gather raw scores: thread (j,h)
    if (t < 64){
      int j = t >> 3, h2 = t & 7;
      if (j < cc) sSc[j][h2] = a_src[(size_t)sIdx[j]*NH + h2];
    }
    __syncthreads();
    if (t < 8){
      int h = t;
      float m = sM[h], d = sD[h], ad = sAd[h];
      float e[8], mc = -1e30f;
#pragma unroll
      for (int j = 0; j < 8; j++){
        if (j < cc){
          float ee = sSc[j][h] + ad;
          ee = ee > 0.f ? ee : NEG*ee;
          e[j] = ee; mc = fmaxf(mc, ee);
        } else e[j] = -1e30f;
      }
      float rsc = 1.f;
      if (mc > m){ rsc = __expf(m - mc); d *= rsc; m = mc; }
      sR[h] = rsc;
#pragma unroll
      for (int j = 0; j < 8; j++){
        float w = (j < cc) ? __expf(e[j] - m) : 0.f;
        sW[j][h] = w; d += w;
      }
      sM[h] = m; sD[h] = d;
    }
    __syncthreads();
    acc *= sR[hh];
#pragma unroll
    for (int j = 0; j < 8; j++) acc += sW[j][hh] * xv[j];
  }
  __syncthreads();
  hout[(size_t)nid*D + t] = f2b(acc / sD[hh] + bg[t]);
}

// ---------------- BatchNorm stats over bf16 h ----------------
__global__ __launch_bounds__(256) void k_bnstats(const ushort* __restrict__ h, float* __restrict__ sums, int n){
  int c = threadIdx.x & 127;
  int half = threadIdx.x >> 7;
  float s = 0.f, s2 = 0.f;
  for (int r = blockIdx.x*2 + half; r < n; r += gridDim.x*2){
    float v = bf2f(h[(size_t)r*D + c]);
    s += v; s2 += v*v;
  }
  __shared__ float sh[256], sh2[256];
  sh[threadIdx.x] = s; sh2[threadIdx.x] = s2;
  __syncthreads();
  if (half == 0){
    s  = sh[c]  + sh[128 + c];
    s2 = sh2[c] + sh2[128 + c];
    atomicAdd(&sums[c], s);
    atomicAdd(&sums[128 + c], s2);
  }
}

__global__ void k_bnfinal(const float* __restrict__ sums, const float* __restrict__ gamma,
                          const float* __restrict__ beta, float* __restrict__ bnsc, int n){
  int c = threadIdx.x;
  float invn = 1.0f / (float)n;
  float mu = sums[c] * invn;
  float var = sums[128 + c] * invn - mu*mu;
  float sc = gamma[c] * rsqrtf(var + BN_EPS);
  bnsc[c] = sc;
  bnsc[128 + c] = beta[c] - mu*sc;
}

__global__ void k_bnsc_init(float* __restrict__ bnsc){
  int c = threadIdx.x;
  bnsc[c] = 1.0f;
  bnsc[128 + c] = 0.0f;
}

// ---------------- global mean pool with fused BN+ReLU ----------------
__global__ __launch_bounds__(128) void k_pool(const ushort* __restrict__ h, const int* __restrict__ batch,
                                              const float* __restrict__ bnsc,
                                              float* __restrict__ pooled, int n){
  int g = blockIdx.x;
  __shared__ int se[2];
  if (threadIdx.x == 0){
    int lo = 0, hi = n;
    while (lo < hi){ int mid = (lo + hi) >> 1; if (batch[mid] < g) lo = mid + 1; else hi = mid; }
    se[0] = lo;
    lo = se[0]; hi = n;
    while (lo < hi){ int mid = (lo + hi) >> 1; if (batch[mid] < g + 1) lo = mid + 1; else hi = mid; }
    se[1] = lo;
  }
  __syncthreads();
  int st = se[0], en = se[1];
  float sc = bnsc[threadIdx.x], sh = bnsc[128 + threadIdx.x];
  float s = 0.f;
  for (int r = st; r < en; r++){
    float v = bf2f(h[(size_t)r*D + threadIdx.x]) * sc + sh;
    s += v > 0.f ? v : 0.f;
  }
  float cnt = (float)(en - st);
  pooled[(size_t)g*D + threadIdx.x] = s / fmaxf(cnt, 1.0f);
}

// ---------------- output heads ----------------
__global__ __launch_bounds__(64) void k_heads(const float* __restrict__ pooled,
                                              const float* __restrict__ hW1, const float* __restrict__ hb1,
                                              const float* __restrict__ hW2, const float* __restrict__ hb2,
                                              float* __restrict__ out){
  int g = blockIdx.x;
  int m = threadIdx.x;
  __shared__ float sp[128];
  sp[m]      = pooled[(size_t)g*D + m];
  sp[m + 64] = pooled[(size_t)g*D + m + 64];
  __syncthreads();
#pragma unroll
  for (int k = 0; k < 3; k++){
    float acc = hb1[k*64 + m];
    const float* w = hW1 + k*8192 + m;
    for (int d = 0; d < 128; d++) acc += sp[d] * w[d*64];
    float val = fmaxf(acc, 0.f) * hW2[k*64 + m];
    for (int off = 32; off; off >>= 1) val += __shfl_down(val, off);
    if (m == 0) out[g*3 + k] = val + hb2[k];
  }
}

// ---------------- launch ----------------
extern "C" void kernel_launch(void* const* d_in, const int* in_sizes, int n_in,
                              void* d_out, int out_size, void* d_ws, size_t ws_size,
                              hipStream_t stream){
  const float* x    = (const float*)d_in[0];
  const int*   ei   = (const int*)d_in[1];
  const int*   batch= (const int*)d_in[2];
  const float* Wp   = (const float*)d_in[3];
  const float* bp   = (const float*)d_in[4];
  const float* Wg   = (const float*)d_in[5];
  const float* asrc = (const float*)d_in[6];
  const float* adst = (const float*)d_in[7];
  const float* bg   = (const float*)d_in[8];
  const float* gamma= (const float*)d_in[9];
  const float* beta = (const float*)d_in[10];
  const float* hW1  = (const float*)d_in[11];
  const float* hb1  = (const float*)d_in[12];
  const float* hW2  = (const float*)d_in[13];
  const float* hb2  = (const float*)d_in[14];
  float* out = (float*)d_out;

  const int E = in_sizes[1] / 2;
  const int N = in_sizes[2];
  const int G = out_size / 3;
  const int WTOT = in_sizes[5];           // L*D*D

  char* w = (char*)d_ws;
  auto alloc = [&](size_t bytes){ char* p = w; w += (bytes + 255) & ~(size_t)255; return p; };
  ushort* h     = (ushort*)alloc((size_t)N*D*2);
  ushort* xh    = (ushort*)alloc((size_t)N*D*2);
  float* a_src  = (float*)alloc((size_t)N*NH*4);
  float* a_dst  = (float*)alloc((size_t)N*NH*4);
  int*   deg    = (int*)  alloc((size_t)N*4);
  int*   rp     = (int*)  alloc((size_t)N*4);
  int*   cursor = (int*)  alloc((size_t)N*4);
  int*   col    = (int*)  alloc((size_t)E*4);
  int*   bsum   = (int*)  alloc(512*4);
  float* bnsum  = (float*)alloc(256*4);
  float* bnsc   = (float*)alloc(256*4);
  ushort* WtB   = (ushort*)alloc((size_t)WTOT*2);
  float* pooled = (float*)alloc((size_t)G*D*4);

  const int nb = (N + 255) / 256;

  hipMemsetAsync(deg, 0, (size_t)N*4, stream);
  k_hist   <<<(E + 255)/256, 256, 0, stream>>>(ei, deg, E);
  k_scan1  <<<nb, 256, 0, stream>>>(deg, rp, bsum, N);
  k_scan2  <<<1, 512, 0, stream>>>(bsum, nb);
  k_scan3  <<<nb, 256, 0, stream>>>(rp, cursor, bsum, N);
  k_scatter<<<(E + 255)/256, 256, 0, stream>>>(ei, cursor, col, E);

  k_wprep<<<(WTOT + 255)/256, 256, 0, stream>>>(Wg, WtB, WTOT);
  k_init <<<(N*D + 255)/256, 256, 0, stream>>>(x, Wp, bp, h, N);
  k_bnsc_init<<<1, 128, 0, stream>>>(bnsc);

  for (int l = 0; l < 4; l++){
    k_gemm  <<<(N + 127)/128, 256, 0, stream>>>(h, WtB + l*D*D, xh, bnsc, N);
    k_scores<<<(N*NH + 255)/256, 256, 0, stream>>>(xh, asrc + l*NH*CH, adst + l*NH*CH, a_src, a_dst, N);
    k_agg   <<<N, 128, 0, stream>>>(xh, a_src, a_dst, rp, deg, col, bg + l*D, h, N);
    hipMemsetAsync(bnsum, 0, 256*4, stream);
    k_bnstats<<<256, 256, 0, stream>>>(h, bnsum, N);
    k_bnfinal<<<1, 128, 0, stream>>>(bnsum, gamma + l*D, beta + l*D, bnsc, N);
  }

  k_pool <<<G, 128, 0, stream>>>(h, batch, bnsc, pooled, N);
  k_heads<<<G, 64, 0, stream>>>(pooled, hW1, hb1, hW2, hb2, out);
}

// Round 4
// 661.763 us; speedup vs baseline: 1.5891x; 1.2715x over previous
//
#include <hip/hip_runtime.h>

#define D 128
#define NH 8
#define CH 16
#define NEG 0.2f
#define BN_EPS 1e-5f
#define MAXDEG 32

typedef unsigned int uint;
typedef unsigned short ushort;
typedef __attribute__((ext_vector_type(8))) short bfrag;
typedef __attribute__((ext_vector_type(4))) float ffrag;

__device__ __forceinline__ float bf_lo(uint u){ return __uint_as_float(u << 16); }
__device__ __forceinline__ float bf_hi(uint u){ return __uint_as_float(u & 0xffff0000u); }
__device__ __forceinline__ float bf2f(ushort s){ return __uint_as_float(((uint)s) << 16); }
__device__ __forceinline__ ushort f2b(float f){
  uint u = __float_as_uint(f);
  u += 0x7fffu + ((u >> 16) & 1u);      // round-to-nearest-even
  return (ushort)(u >> 16);
}

// ---------------- CSR build: slotted scatter, deg doubles as cursor ----------------
__global__ void k_scatter(const int* __restrict__ ei, int* __restrict__ deg,
                          int* __restrict__ col, int E){
  int e = blockIdx.x*blockDim.x + threadIdx.x;
  if (e < E){
    int d = ei[E + e];
    int pos = atomicAdd(&deg[d], 1);
    if (pos < MAXDEG) col[(size_t)d*MAXDEG + pos] = ei[e];
  }
}

// ---------------- weight prep: WtB[l][n][k] = bf16(Wg[l][k][n]) ----------------
__global__ void k_wprep(const float* __restrict__ Wg, ushort* __restrict__ WtB, int total){
  int i = blockIdx.x*256 + threadIdx.x;
  if (i >= total) return;
  int l = i >> 14, r = i & 16383, nn = r >> 7, kk = r & 127;
  WtB[i] = f2b(Wg[l*16384 + kk*128 + nn]);
}

// ---------------- input projection: h = relu(x @ Wp + bp), bf16 out ----------------
__global__ void k_init(const float* __restrict__ x, const float* __restrict__ Wp,
                       const float* __restrict__ bp, ushort* __restrict__ h, int n){
  int i = blockIdx.x*blockDim.x + threadIdx.x;
  if (i >= n*D) return;
  int nid = i >> 7, d = i & 127;
  const float* xr = x + nid*16;
  float s = bp[d];
#pragma unroll
  for (int k = 0; k < 16; k++) s += xr[k] * Wp[k*D + d];
  h[i] = f2b(s > 0.f ? s : 0.f);
}

// ---------------- MFMA bf16 GEMM: fused BN-final(prologue) + BN+ReLU(A-load) + scores(epilogue) ----
__global__ __launch_bounds__(256) void k_gemm(const ushort* __restrict__ hin,
                                              const ushort* __restrict__ WtB,
                                              ushort* __restrict__ xh,
                                              float* __restrict__ a_srcO,
                                              float* __restrict__ a_dstO,
                                              const float* __restrict__ bnsum,
                                              const float* __restrict__ gamma,
                                              const float* __restrict__ beta,
                                              const float* __restrict__ asrcL,
                                              const float* __restrict__ adstL,
                                              int n, int first){
  __shared__ ushort sm[2*128*72];          // hL | wL
  __shared__ float sS[128], sB[128];
  ushort* hL = sm;
  ushort* wL = sm + 128*72;
  int t = threadIdx.x;
  int wid = t >> 6, lane = t & 63, l15 = lane & 15, quad = lane >> 4;
  int n0 = blockIdx.x * 128;

  if (t < 128){
    float sc, sh;
    if (first){ sc = 1.f; sh = 0.f; }
    else {
      float invn = 1.0f / (float)n;
      float mu = bnsum[t] * invn;
      float var = bnsum[128 + t] * invn - mu*mu;
      sc = gamma[t] * rsqrtf(var + BN_EPS);
      sh = beta[t] - mu*sc;
    }
    sS[t] = sc; sB[t] = sh;
  }

  ffrag acc[2][8];
#pragma unroll
  for (int mt = 0; mt < 2; mt++)
#pragma unroll
    for (int nt = 0; nt < 8; nt++) acc[mt][nt] = (ffrag){0.f,0.f,0.f,0.f};

  __syncthreads();

  for (int kc = 0; kc < 128; kc += 64){
    // stage A (h) with BN+ReLU: 128 rows x 64 k
#pragma unroll
    for (int i = 0; i < 4; i++){
      int u = t + i*256;
      int r = u >> 3, k8 = u & 7;
      int row = n0 + r;
      uint4 v = make_uint4(0,0,0,0);
      if (row < n) v = *(const uint4*)(hin + (size_t)row*D + kc + k8*8);
      int kb = kc + k8*8;
      float f[8] = { bf_lo(v.x), bf_hi(v.x), bf_lo(v.y), bf_hi(v.y),
                     bf_lo(v.z), bf_hi(v.z), bf_lo(v.w), bf_hi(v.w) };
      union { ushort us[8]; uint4 u4; } o;
#pragma unroll
      for (int j = 0; j < 8; j++){
        float xv = f[j]*sS[kb + j] + sB[kb + j];
        o.us[j] = f2b(xv > 0.f ? xv : 0.f);
      }
      *(uint4*)(hL + r*72 + k8*8) = o.u4;
    }
    // stage B (Wt): 128 n x 64 k (already bf16, [n][k])
#pragma unroll
    for (int i = 0; i < 4; i++){
      int u = t + i*256;
      int r = u >> 3, k8 = u & 7;
      uint4 v = *(const uint4*)(WtB + (size_t)r*D + kc + k8*8);
      *(uint4*)(wL + r*72 + k8*8) = v;
    }
    __syncthreads();

    bfrag a[2][2];
#pragma unroll
    for (int mt = 0; mt < 2; mt++)
#pragma unroll
      for (int ks = 0; ks < 2; ks++)
        a[mt][ks] = *(const bfrag*)(hL + (wid*32 + mt*16 + l15)*72 + ks*32 + quad*8);

#pragma unroll
    for (int nt = 0; nt < 8; nt++){
#pragma unroll
      for (int ks = 0; ks < 2; ks++){
        bfrag b = *(const bfrag*)(wL + (nt*16 + l15)*72 + ks*32 + quad*8);
        acc[0][nt] = __builtin_amdgcn_mfma_f32_16x16x32_bf16(a[0][ks], b, acc[0][nt], 0, 0, 0);
        acc[1][nt] = __builtin_amdgcn_mfma_f32_16x16x32_bf16(a[1][ks], b, acc[1][nt], 0, 0, 0);
      }
    }
    __syncthreads();
  }

  // epilogue: repack C via LDS (row = wid*32+mt*16+quad*4+r, col = nt*16+l15)
  ushort* oL = sm;                          // 128*136 ushorts
#pragma unroll
  for (int mt = 0; mt < 2; mt++)
#pragma unroll
    for (int nt = 0; nt < 8; nt++)
#pragma unroll
      for (int r = 0; r < 4; r++){
        int row = wid*32 + mt*16 + quad*4 + r;
        oL[row*136 + nt*16 + l15] = f2b(acc[mt][nt][r]);
      }
  __syncthreads();
  // vectorized store of xh
#pragma unroll
  for (int i = 0; i < 8; i++){
    int u = t + i*256;
    int row = u >> 4, c8 = u & 15;
    int grow = n0 + row;
    if (grow < n)
      *(uint4*)(xh + (size_t)grow*D + c8*8) = *(const uint4*)(oL + row*136 + c8*8);
  }
  // fused attention scores: 128 rows x 8 heads, 4 (row,head) pairs per thread
#pragma unroll
  for (int q = 0; q < 4; q++){
    int id = t*4 + q;
    int r = id >> 3, h8 = id & 7;
    int grow = n0 + r;
    if (grow < n){
      const ushort* rowp = oL + r*136 + h8*16;
      uint4 v0 = *(const uint4*)(rowp);
      uint4 v1 = *(const uint4*)(rowp + 8);
      float f[16] = { bf_lo(v0.x), bf_hi(v0.x), bf_lo(v0.y), bf_hi(v0.y),
                      bf_lo(v0.z), bf_hi(v0.z), bf_lo(v0.w), bf_hi(v0.w),
                      bf_lo(v1.x), bf_hi(v1.x), bf_lo(v1.y), bf_hi(v1.y),
                      bf_lo(v1.z), bf_hi(v1.z), bf_lo(v1.w), bf_hi(v1.w) };
      float s1 = 0.f, s2 = 0.f;
      const float* ap = asrcL + h8*CH;
      const float* dp = adstL + h8*CH;
#pragma unroll
      for (int i = 0; i < 16; i++){ s1 += f[i]*ap[i]; s2 += f[i]*dp[i]; }
      a_srcO[(size_t)grow*NH + h8] = s1;
      a_dstO[(size_t)grow*NH + h8] = s2;
    }
  }
}

// ---------------- wave-per-node aggregation, zero barriers ----------------
// block 256 = 4 waves, one node per wave. Lane l: channels (2l,2l+1), head hc=l>>3.
// Score role: lane (j,h) = (l>>3, l&7) handles edge slot j, head h.
__global__ __launch_bounds__(256) void k_agg(const uint* __restrict__ xh32,
                                             const float* __restrict__ a_src,
                                             const float* __restrict__ a_dst,
                                             const int* __restrict__ deg,
                                             const int* __restrict__ col,
                                             const float* __restrict__ bg,
                                             ushort* __restrict__ hout, int n){
  int wv = threadIdx.x >> 6;
  int l  = threadIdx.x & 63;
  int nid = blockIdx.x*4 + wv;
  if (nid >= n) return;

  int hs = l & 7;      // score-role head
  int j  = l >> 3;     // score-role edge slot
  int hc = l >> 3;     // channel-role head

  float ad = a_dst[(size_t)nid*NH + hs];
  float e0 = a_src[(size_t)nid*NH + hs] + ad;
  e0 = e0 > 0.f ? e0 : NEG*e0;
  float m = e0, d = 1.f;

  uint selfv = xh32[(size_t)nid*64 + l];
  float acc0 = bf_lo(selfv), acc1 = bf_hi(selfv);

  int cnt = deg[nid];
  if (cnt > MAXDEG) cnt = MAXDEG;
  const int* cbase = col + (size_t)nid*MAXDEG;

  for (int c0 = 0; c0 < cnt; c0 += 8){
    int cc = cnt - c0; if (cc > 8) cc = 8;
    int sj = nid;
    if (j < cc) sj = cbase[c0 + j];
    float av = (j < cc) ? a_src[(size_t)sj*NH + hs] : 0.f;
    // broadcast edge indices, gather neighbor rows (independent loads)
    int scc[8];
#pragma unroll
    for (int jj = 0; jj < 8; jj++) scc[jj] = __shfl(sj, jj*8);
    float xv0[8], xv1[8];
#pragma unroll
    for (int jj = 0; jj < 8; jj++){
      if (jj < cc){
        uint v = xh32[(size_t)scc[jj]*64 + l];
        xv0[jj] = bf_lo(v); xv1[jj] = bf_hi(v);
      } else { xv0[jj] = 0.f; xv1[jj] = 0.f; }
    }
    // scores
    float e = -1e30f;
    if (j < cc){
      e = av + ad;
      e = e > 0.f ? e : NEG*e;
    }
    // per-head max over j: lanes with equal hs are stride-8 -> xor 8,16,32
    float mc = e;
    mc = fmaxf(mc, __shfl_xor(mc, 8));
    mc = fmaxf(mc, __shfl_xor(mc, 16));
    mc = fmaxf(mc, __shfl_xor(mc, 32));
    float mnew = fmaxf(m, mc);
    float rsc = __expf(m - mnew);
    float w = (j < cc) ? __expf(e - mnew) : 0.f;
    float ws = w;
    ws += __shfl_xor(ws, 8);
    ws += __shfl_xor(ws, 16);
    ws += __shfl_xor(ws, 32);
    d = d * rsc + ws;
    m = mnew;
    // channel role: rescale + weighted accumulate
    float rc = __shfl(rsc, hc);          // lane hc<8 has hs==hc
    acc0 *= rc; acc1 *= rc;
#pragma unroll
    for (int jj = 0; jj < 8; jj++){
      if (jj < cc){
        float wj = __shfl(w, jj*8 + hc);
        acc0 += wj * xv0[jj];
        acc1 += wj * xv1[jj];
      }
    }
  }
  float dfin = __shfl(d, hc);
  float inv = 1.0f / dfin;
  float b0 = bg[2*l], b1 = bg[2*l + 1];
  uint o = ((uint)f2b(acc0*inv + b0)) | (((uint)f2b(acc1*inv + b1)) << 16);
  ((uint*)hout)[(size_t)nid*64 + l] = o;
}

// ---------------- BatchNorm stats (uint loads, 2 channels/lane) ----------------
__global__ __launch_bounds__(256) void k_bnstats(const uint* __restrict__ h32, float* __restrict__ sums, int n){
  int c2 = threadIdx.x & 63;
  int rq = threadIdx.x >> 6;
  float s0=0.f, s1=0.f, q0=0.f, q1=0.f;
  for (int r = blockIdx.x*4 + rq; r < n; r += gridDim.x*4){
    uint v = h32[(size_t)r*64 + c2];
    float a = bf_lo(v), b = bf_hi(v);
    s0 += a; q0 += a*a; s1 += b; q1 += b*b;
  }
  __shared__ float shS[4][64][2], shQ[4][64][2];
  shS[rq][c2][0] = s0; shS[rq][c2][1] = s1;
  shQ[rq][c2][0] = q0; shQ[rq][c2][1] = q1;
  __syncthreads();
  int t = threadIdx.x;
  if (t < 128){
    int c2i = t >> 1, p = t & 1;
    float ss = shS[0][c2i][p] + shS[1][c2i][p] + shS[2][c2i][p] + shS[3][c2i][p];
    float qq = shQ[0][c2i][p] + shQ[1][c2i][p] + shQ[2][c2i][p] + shQ[3][c2i][p];
    int c = c2i*2 + p;
    atomicAdd(&sums[c], ss);
    atomicAdd(&sums[128 + c], qq);
  }
}

// ---------------- global mean pool, fused last-layer BN+ReLU ----------------
__global__ __launch_bounds__(128) void k_pool(const ushort* __restrict__ h, const int* __restrict__ batch,
                                              const float* __restrict__ bnsum,
                                              const float* __restrict__ gamma,
                                              const float* __restrict__ beta,
                                              float* __restrict__ pooled, int n){
  int g = blockIdx.x;
  int t = threadIdx.x;
  __shared__ int se[2];
  if (t == 0){
    int lo = 0, hi = n;
    while (lo < hi){ int mid = (lo + hi) >> 1; if (batch[mid] < g) lo = mid + 1; else hi = mid; }
    se[0] = lo;
    lo = se[0]; hi = n;
    while (lo < hi){ int mid = (lo + hi) >> 1; if (batch[mid] < g + 1) lo = mid + 1; else hi = mid; }
    se[1] = lo;
  }
  float invn = 1.0f / (float)n;
  float mu = bnsum[t] * invn;
  float var = bnsum[128 + t] * invn - mu*mu;
  float sc = gamma[t] * rsqrtf(var + BN_EPS);
  float sh = beta[t] - mu*sc;
  __syncthreads();
  int st = se[0], en = se[1];
  float s = 0.f;
  for (int r = st; r < en; r++){
    float v = bf2f(h[(size_t)r*D + t]) * sc + sh;
    s += v > 0.f ? v : 0.f;
  }
  float cnt = (float)(en - st);
  pooled[(size_t)g*D + t] = s / fmaxf(cnt, 1.0f);
}

// ---------------- output heads ----------------
__global__ __launch_bounds__(64) void k_heads(const float* __restrict__ pooled,
                                              const float* __restrict__ hW1, const float* __restrict__ hb1,
                                              const float* __restrict__ hW2, const float* __restrict__ hb2,
                                              float* __restrict__ out){
  int g = blockIdx.x;
  int m = threadIdx.x;
  __shared__ float sp[128];
  sp[m]      = pooled[(size_t)g*D + m];
  sp[m + 64] = pooled[(size_t)g*D + m + 64];
  __syncthreads();
#pragma unroll
  for (int k = 0; k < 3; k++){
    float acc = hb1[k*64 + m];
    const float* w = hW1 + k*8192 + m;
    for (int d = 0; d < 128; d++) acc += sp[d] * w[d*64];
    float val = fmaxf(acc, 0.f) * hW2[k*64 + m];
    for (int off = 32; off; off >>= 1) val += __shfl_down(val, off);
    if (m == 0) out[g*3 + k] = val + hb2[k];
  }
}

// ---------------- launch ----------------
extern "C" void kernel_launch(void* const* d_in, const int* in_sizes, int n_in,
                              void* d_out, int out_size, void* d_ws, size_t ws_size,
                              hipStream_t stream){
  const float* x    = (const float*)d_in[0];
  const int*   ei   = (const int*)d_in[1];
  const int*   batch= (const int*)d_in[2];
  const float* Wp   = (const float*)d_in[3];
  const float* bp   = (const float*)d_in[4];
  const float* Wg   = (const float*)d_in[5];
  const float* asrc = (const float*)d_in[6];
  const float* adst = (const float*)d_in[7];
  const float* bg   = (const float*)d_in[8];
  const float* gamma= (const float*)d_in[9];
  const float* beta = (const float*)d_in[10];
  const float* hW1  = (const float*)d_in[11];
  const float* hb1  = (const float*)d_in[12];
  const float* hW2  = (const float*)d_in[13];
  const float* hb2  = (const float*)d_in[14];
  float* out = (float*)d_out;

  const int E = in_sizes[1] / 2;
  const int N = in_sizes[2];
  const int G = out_size / 3;
  const int WTOT = in_sizes[5];           // L*D*D

  char* w = (char*)d_ws;
  auto alloc = [&](size_t bytes){ char* p = w; w += (bytes + 255) & ~(size_t)255; return p; };
  ushort* h     = (ushort*)alloc((size_t)N*D*2);
  ushort* xh    = (ushort*)alloc((size_t)N*D*2);
  float* a_src  = (float*)alloc((size_t)N*NH*4);
  float* a_dst  = (float*)alloc((size_t)N*NH*4);
  int*   deg    = (int*)  alloc((size_t)N*4);
  int*   col    = (int*)  alloc((size_t)N*MAXDEG*4);
  float* bnsum  = (float*)alloc(256*4);
  ushort* WtB   = (ushort*)alloc((size_t)WTOT*2);
  float* pooled = (float*)alloc((size_t)G*D*4);

  hipMemsetAsync(deg, 0, (size_t)N*4, stream);
  k_scatter<<<(E + 255)/256, 256, 0, stream>>>(ei, deg, col, E);

  k_wprep<<<(WTOT + 255)/256, 256, 0, stream>>>(Wg, WtB, WTOT);
  k_init <<<(N*D + 255)/256, 256, 0, stream>>>(x, Wp, bp, h, N);

  for (int l = 0; l < 4; l++){
    k_gemm<<<(N + 127)/128, 256, 0, stream>>>(h, WtB + l*D*D, xh, a_src, a_dst,
                                              bnsum, gamma + l*D, beta + l*D,
                                              asrc + l*NH*CH, adst + l*NH*CH, N, l == 0);
    k_agg<<<(N + 3)/4, 256, 0, stream>>>((const uint*)xh, a_src, a_dst, deg, col,
                                         bg + l*D, h, N);
    hipMemsetAsync(bnsum, 0, 256*4, stream);
    k_bnstats<<<256, 256, 0, stream>>>((const uint*)h, bnsum, N);
  }

  k_pool <<<G, 128, 0, stream>>>(h, batch, bnsum, gamma + 3*D, beta + 3*D, pooled, N);
  k_heads<<<G, 64, 0, stream>>>(pooled, hW1, hb1, hW2, hb2, out);
}